// Round 15
// baseline (6196.746 us; speedup 1.0000x reference)
//
#include <hip/hip_runtime.h>

// CustomLSTM on MI355X. R15: two decoupled 128-block barrier domains
// (layer 0 / layer 1), full-K waves (no LDS exchange), weights LDS-resident
// fragment-major, oct h-rings (h0 depth 8 + lag guard, h1 depth 2),
// coalesced 8B h stores, arrival-time acquire-inv, x@Wx0 in overlap window.

#define NBLK 256
#define TPB  512
#define T_   512
#define HS_OFF 33554432   // outputs floats
#define CS_OFF 33685504   // HS_OFF + 2*64*1024

typedef float  f32x4  __attribute__((ext_vector_type(4)));
typedef short  bf16x8 __attribute__((ext_vector_type(8)));

// ---- workspace byte offsets ----
#define WS_CTR  0u              // 40960: gctr0[8][512]|rctr0|flag0|gctr1[8][512]|rctr1|flag1
#define WS_W    40960u          // 4 * (4096*1024) bf16 = 32 MiB (permuted, [m][p][k])
#define WS_BIAS 33595392u       // 2*4096 f32
#define WS_XB   33628160u       // [T][B][D] bf16 = 64 MiB
#define WS_H0   100737024u      // ring: 8 slots x 65536 bf16, layout [oct][row][8]
#define WS_H1   101785600u      // ring: 2 slots x 65536 bf16
#define WS_MIN  102047744u

__device__ __forceinline__ unsigned short f2bf(float f) {
  union { float f; unsigned u; } v; v.f = f;
  return (unsigned short)((v.u + 0x7FFFu + ((v.u >> 16) & 1u)) >> 16);
}
__device__ __forceinline__ float fsig(float x) { return 1.0f / (1.0f + __expf(-x)); }
__device__ __forceinline__ float ftanh(float x) {
  x = fminf(15.0f, fmaxf(-15.0f, x));
  float e = __expf(2.0f * x);
  return (e - 1.0f) / (e + 1.0f);
}

// Permute+transpose+bf16 the 4 weight matrices: out[m][p][k] = bf16(W_m[k][orig(p)]),
// orig(p) = (p&3)*1024 + (p>>2)  (p = 4*j + gate). 64x64 tiles via LDS.
__global__ void kw(const float* __restrict__ Wx0, const float* __restrict__ Wh0,
                   const float* __restrict__ Wx1, const float* __restrict__ Wh1,
                   unsigned short* __restrict__ wp) {
  __shared__ float tile[64][65];
  int tb = blockIdx.x;
  int m  = tb >> 10;
  int kt = (tb >> 6) & 15;
  int nt = tb & 63;
  const float* W = (m == 0) ? Wx0 : (m == 1) ? Wh0 : (m == 2) ? Wx1 : Wh1;
  unsigned short* O = wp + (size_t)m * 4194304u;
  int k0 = kt * 64, n0 = nt * 64;
  int tx = threadIdx.x & 63, tg = threadIdx.x >> 6;
  for (int r = tg; r < 64; r += 4)
    tile[r][tx] = W[(size_t)(k0 + r) * 4096 + n0 + tx];
  __syncthreads();
  for (int r = tg; r < 64; r += 4) {
    int n = n0 + r;
    int p = ((n & 1023) << 2) | (n >> 10);
    O[(size_t)p * 1024 + k0 + tx] = f2bf(tile[tx][r]);
  }
}

// x [B][T][D] f32 -> xb [T*B][D] bf16 (row = t*64+b)
__global__ void kx(const float* __restrict__ x, unsigned short* __restrict__ xb) {
  int row = blockIdx.x;
  int t = row >> 6, b = row & 63;
  const float4* src = (const float4*)(x + ((size_t)b * 512 + t) * 1024);
  float4 f = src[threadIdx.x];
  ushort4 o; o.x = f2bf(f.x); o.y = f2bf(f.y); o.z = f2bf(f.z); o.w = f2bf(f.w);
  ((ushort4*)(xb + (size_t)row * 1024))[threadIdx.x] = o;
}

// bias permute + prime rings: h0 init -> slot 7, h1 init -> slot 1 ([oct][row][8])
__global__ void kmisc(const float* __restrict__ b0, const float* __restrict__ b1,
                      const float* __restrict__ h0in,
                      float* __restrict__ biasP,
                      unsigned short* __restrict__ h0r, unsigned short* __restrict__ h1r) {
  int idx = blockIdx.x * 256 + threadIdx.x;
  if (idx < 8192) {
    int layer = idx >> 12, p = idx & 4095;
    int orig = (p & 3) * 1024 + (p >> 2);
    biasP[idx] = (layer ? b1 : b0)[orig];
  } else if (idx < 139264) {
    int e = idx - 8192;
    int layer = e >> 16, o = e & 65535;
    int row = o >> 10, col = o & 1023;
    unsigned short v = f2bf(h0in[layer * 65536 + o]);
    int ds = (col >> 3) * 512 + row * 8 + (col & 7);
    if (layer) h1r[65536 + ds] = v;            // slot 1 (= step -1)
    else       h0r[7 * 65536 + ds] = v;        // slot 7 (= step -1 mod 8)
  }
}

// Persistent cooperative kernel. 256 blocks x 512 threads.
// Blocks 0-127: layer 0 domain. Blocks 128-255: layer 1 domain.
// Per block: 32 gate-cols (8 h-cols); wave w = (cg=w>>2, rt=w&3): one 16x16
// output tile, full K=1024. Weights fragment-major in LDS.
__global__ void __launch_bounds__(TPB, 2)
klstm(const float* __restrict__ c0_in,
      const unsigned short* __restrict__ wp,
      const float* __restrict__ biasP,
      const unsigned short* __restrict__ xb,
      unsigned short* __restrict__ h0ring,
      unsigned short* __restrict__ h1ring,
      unsigned* __restrict__ ctrbase,
      float* __restrict__ out) {
  extern __shared__ char smem[];           // 64K W_rec | 64K W_in | 2K lh
  float* lhb = (float*)(smem + 131072);
  unsigned* gctr0 = ctrbase;               // [8][512]
  unsigned* rctr0 = ctrbase + 4096;        // [512]
  unsigned* flag0 = ctrbase + 4608;        // [512]
  unsigned* gctr1 = ctrbase + 5120;        // [8][512]
  unsigned* rctr1 = ctrbase + 9216;        // [512]
  unsigned* flag1 = ctrbase + 9728;        // [512]
  const int tid = threadIdx.x;
  const int w   = tid >> 6;
  const int l   = tid & 63;
  const int bid = blockIdx.x;
  const int isL1 = bid >> 7;
  const int b    = bid & 127;
  const int cg   = w >> 2;                 // 0,1: 16-gate-col group
  const int rbase = (w & 3) * 16;          // batch-row tile
  const int n0   = b * 32;                 // gate-col base
  const int grp  = b >> 4;                 // 8 groups x 16 blocks
  float* lh = lhb + w * 64;

  // stage weights fragment-major: slot0 = recurrent (Wh0/Wh1), slot1 = input (Wx0/Wx1)
  {
    const int mA = isL1 ? 3 : 1;
    const int mB = isL1 ? 2 : 0;
    for (int s = 0; s < 2; ++s) {
      int m = s ? mB : mA;
      const char* src = (const char*)(wp + (size_t)m * 4194304u + (size_t)n0 * 1024u);
      char* dst = smem + s * 65536;
      for (int i = tid; i < 4096; i += TPB) {
        int kreg = i & 3, col = (i >> 2) & 15, kk = (i >> 6) & 31, cgg = i >> 11;
        int srcb = (cgg * 16 + col) * 2048 + kk * 64 + kreg * 16;
        *(uint4*)(dst + i * 16) = *(const uint4*)(src + srcb);
      }
    }
  }

  const float biasv = biasP[isL1 * 4096 + n0 + cg * 16 + (l & 15)];
  const int qb = l & ~3;
  const int jg = b * 8 + cg * 4 + ((l & 15) >> 2);   // h-col within layer

  float cr[4];
  #pragma unroll
  for (int v = 0; v < 4; ++v)
    cr[v] = c0_in[isL1 * 65536 + (rbase + (l >> 4) * 4 + v) * 1024 + jg];

  const int hfb   = (l >> 4) * 512 + (rbase + (l & 15)) * 8;   // + kk*2048
  const int bfrag = ((l & 15) * 4 + (l >> 4)) * 16;            // 16B unit in 1KB
  const int ae0   = (rbase + (l & 15)) * 1024 + (l >> 4) * 8;  // xb + kk*32
  const int bslot0 = cg * 32768;            // recurrent W fragments
  const int bslot1 = 65536 + cg * 32768;    // input W fragments
  const int hsto  = b * 512 + cg * 4;       // + (rbase+l)*8, 8B per lane

  __syncthreads();                          // weights visible

  // L0 prologue: x[0] @ Wx0 (full K, own tile)
  f32x4 xacc = {0.f, 0.f, 0.f, 0.f};
  if (!isL1) {
    #pragma unroll
    for (int kk = 0; kk < 32; ++kk) {
      bf16x8 ax = *(const bf16x8*)(xb + ae0 + kk * 32);
      bf16x8 bx = *(const bf16x8*)(smem + bslot1 + kk * 1024 + bfrag);
      xacc = __builtin_amdgcn_mfma_f32_16x16x32_bf16(ax, bx, xacc, 0, 0, 0);
    }
  }

  for (int k = 0; k < T_; ++k) {
    // ---- top-of-step waits ----
    if (tid == 0) {
      unsigned spins = 0;
      if (!isL1) {
        if (k > 0)
          while (__hip_atomic_load(&flag0[k - 1], __ATOMIC_RELAXED, __HIP_MEMORY_SCOPE_AGENT) == 0u)
            { __builtin_amdgcn_s_sleep(1); if (++spins > 67108864u) break; }
        if (k >= 8)
          while (__hip_atomic_load(&flag1[k - 8], __ATOMIC_RELAXED, __HIP_MEMORY_SCOPE_AGENT) == 0u)
            { __builtin_amdgcn_s_sleep(1); if (++spins > 67108864u) break; }
      } else {
        if (k > 0)
          while (__hip_atomic_load(&flag1[k - 1], __ATOMIC_RELAXED, __HIP_MEMORY_SCOPE_AGENT) == 0u)
            { __builtin_amdgcn_s_sleep(1); if (++spins > 67108864u) break; }
        while (__hip_atomic_load(&flag0[k], __ATOMIC_RELAXED, __HIP_MEMORY_SCOPE_AGENT) == 0u)
          { __builtin_amdgcn_s_sleep(1); if (++spins > 67108864u) break; }
      }
    }
    __syncthreads();

    // ---- GEMM (full K per wave, no exchange) ----
    f32x4 a0 = {0.f,0.f,0.f,0.f}, a1 = {0.f,0.f,0.f,0.f};
    f32x4 a2 = {0.f,0.f,0.f,0.f}, a3 = {0.f,0.f,0.f,0.f};
    if (!isL1) {
      const unsigned short* hp = h0ring + (size_t)((k + 7) & 7) * 65536;   // h0[k-1]
      bf16x8 hf[32];
      #pragma unroll
      for (int kk = 0; kk < 32; ++kk) hf[kk] = *(const bf16x8*)(hp + hfb + kk * 2048);
      #pragma unroll
      for (int kk = 0; kk < 32; kk += 2) {
        a0 = __builtin_amdgcn_mfma_f32_16x16x32_bf16(hf[kk],
               *(const bf16x8*)(smem + bslot0 + kk * 1024 + bfrag), a0, 0, 0, 0);
        a1 = __builtin_amdgcn_mfma_f32_16x16x32_bf16(hf[kk + 1],
               *(const bf16x8*)(smem + bslot0 + (kk + 1) * 1024 + bfrag), a1, 0, 0, 0);
      }
    } else {
      const unsigned short* hp0 = h0ring + (size_t)(k & 7) * 65536;        // h0[k]
      const unsigned short* hp1 = h1ring + (size_t)((k + 1) & 1) * 65536;  // h1[k-1]
      #pragma unroll
      for (int kk = 0; kk < 32; kk += 2) {
        bf16x8 f0a = *(const bf16x8*)(hp0 + hfb + kk * 2048);
        bf16x8 f1a = *(const bf16x8*)(hp1 + hfb + kk * 2048);
        bf16x8 f0b = *(const bf16x8*)(hp0 + hfb + (kk + 1) * 2048);
        bf16x8 f1b = *(const bf16x8*)(hp1 + hfb + (kk + 1) * 2048);
        a0 = __builtin_amdgcn_mfma_f32_16x16x32_bf16(f1a,
               *(const bf16x8*)(smem + bslot0 + kk * 1024 + bfrag), a0, 0, 0, 0);
        a2 = __builtin_amdgcn_mfma_f32_16x16x32_bf16(f0a,
               *(const bf16x8*)(smem + bslot1 + kk * 1024 + bfrag), a2, 0, 0, 0);
        a1 = __builtin_amdgcn_mfma_f32_16x16x32_bf16(f1b,
               *(const bf16x8*)(smem + bslot0 + (kk + 1) * 1024 + bfrag), a1, 0, 0, 0);
        a3 = __builtin_amdgcn_mfma_f32_16x16x32_bf16(f0b,
               *(const bf16x8*)(smem + bslot1 + (kk + 1) * 1024 + bfrag), a3, 0, 0, 0);
      }
    }

    f32x4 g = (a0 + a1) + (a2 + a3);
    if (!isL1) {
      #pragma unroll
      for (int v = 0; v < 4; ++v) g[v] += xacc[v];
    }

    // ---- pointwise + coalesced h store ----
    f32x4 outv = {0.f, 0.f, 0.f, 0.f};
    {
      unsigned short* hw = isL1 ? (h1ring + (size_t)(k & 1) * 65536)
                                : (h0ring + (size_t)(k & 7) * 65536);
      #pragma unroll
      for (int v = 0; v < 4; ++v) {
        float gv = g[v] + biasv;
        float gi = __shfl(gv, qb);
        float gf = __shfl(gv, qb | 1);
        float gn = __shfl(gv, qb | 2);
        float go = __shfl(gv, qb | 3);
        float i_ = fsig(gi), f_ = fsig(gf), n_ = ftanh(gn), o_ = fsig(go);
        float c = f_ * cr[v] + i_ * n_;
        cr[v] = c;
        float h = o_ * ftanh(c);
        if ((l & 3) == 0)
          lh[((l >> 4) * 4 + v) * 4 + ((l & 15) >> 2)] = h;
      }
      if (l < 16) {
        f32x4 h4 = *(f32x4*)(lh + l * 4);
        outv = h4;
        ushort4 u4;
        u4.x = f2bf(h4[0]); u4.y = f2bf(h4[1]); u4.z = f2bf(h4[2]); u4.w = f2bf(h4[3]);
        union { ushort4 s; unsigned long long q; } pk; pk.s = u4;
        __hip_atomic_store((unsigned long long*)(hw + hsto + (rbase + l) * 8), pk.q,
                           __ATOMIC_RELAXED, __HIP_MEMORY_SCOPE_AGENT);
      }
    }

    // ---- arrival (own domain tree) + acquire-inv ----
    __syncthreads();                      // drain h stores block-wide
    if (tid == 0) {
      unsigned* gc = (isL1 ? gctr1 : gctr0) + grp * 512 + k;
      unsigned old = __hip_atomic_fetch_add(gc, 1u, __ATOMIC_RELAXED, __HIP_MEMORY_SCOPE_AGENT);
      if (old == 15u) {
        unsigned* rc = (isL1 ? rctr1 : rctr0) + k;
        unsigned oldr = __hip_atomic_fetch_add(rc, 1u, __ATOMIC_RELAXED, __HIP_MEMORY_SCOPE_AGENT);
        if (oldr == 7u)
          __hip_atomic_store(&(isL1 ? flag1 : flag0)[k], 1u,
                             __ATOMIC_RELAXED, __HIP_MEMORY_SCOPE_AGENT);
      }
      __builtin_amdgcn_fence(__ATOMIC_ACQUIRE, "agent");
    }

    // ---- overlap window ----
    if (isL1) {
      if (l < 16) {
        const int row = rbase + l;
        *(f32x4*)(out + (size_t)row * 524288u + (size_t)k * 1024u + b * 8 + cg * 4) = outv;
        if (k == T_ - 1)
          *(f32x4*)(out + HS_OFF + 65536 + row * 1024 + b * 8 + cg * 4) = outv;
      }
    } else {
      if (k == T_ - 1 && l < 16)
        *(f32x4*)(out + HS_OFF + (rbase + l) * 1024 + b * 8 + cg * 4) = outv;
      if (k + 1 < T_) {
        const unsigned short* xt = xb + (size_t)(k + 1) * 65536u;
        f32x4 xa = {0.f, 0.f, 0.f, 0.f};
        #pragma unroll
        for (int kk = 0; kk < 32; ++kk) {
          bf16x8 ax = *(const bf16x8*)(xt + ae0 + kk * 32);
          bf16x8 bx = *(const bf16x8*)(smem + bslot1 + kk * 1024 + bfrag);
          xa = __builtin_amdgcn_mfma_f32_16x16x32_bf16(ax, bx, xa, 0, 0, 0);
        }
        xacc = xa;
      }
    }
  }

  // final cell states
  if ((l & 3) == 0) {
    #pragma unroll
    for (int v = 0; v < 4; ++v)
      out[CS_OFF + isL1 * 65536 + (rbase + (l >> 4) * 4 + v) * 1024 + jg] = cr[v];
  }
}

extern "C" void kernel_launch(void* const* d_in, const int* in_sizes, int n_in,
                              void* d_out, int out_size, void* d_ws, size_t ws_size,
                              hipStream_t stream) {
  const float* x   = (const float*)d_in[0];
  const float* h0  = (const float*)d_in[1];
  const float* c0  = (const float*)d_in[2];
  const float* Wx0 = (const float*)d_in[3];
  const float* Wh0 = (const float*)d_in[4];
  const float* b0  = (const float*)d_in[5];
  const float* Wx1 = (const float*)d_in[6];
  const float* Wh1 = (const float*)d_in[7];
  const float* b1  = (const float*)d_in[8];
  float* out = (float*)d_out;
  char* ws = (char*)d_ws;
  if (ws_size < (size_t)WS_MIN) return;   // workspace too small -> fail loudly

  unsigned* ctr       = (unsigned*)(ws + WS_CTR);
  unsigned short* wp  = (unsigned short*)(ws + WS_W);
  float* biasP        = (float*)(ws + WS_BIAS);
  unsigned short* xbp = (unsigned short*)(ws + WS_XB);
  unsigned short* h0r = (unsigned short*)(ws + WS_H0);
  unsigned short* h1r = (unsigned short*)(ws + WS_H1);

  (void)hipMemsetAsync(ctr, 0, 40960, stream);
  hipLaunchKernelGGL(kw,    dim3(4096),  dim3(256), 0, stream, Wx0, Wh0, Wx1, Wh1, wp);
  hipLaunchKernelGGL(kx,    dim3(32768), dim3(256), 0, stream, x, xbp);
  hipLaunchKernelGGL(kmisc, dim3(544),   dim3(256), 0, stream, b0, b1, h0, biasP, h0r, h1r);

  (void)hipFuncSetAttribute((const void*)klstm, hipFuncAttributeMaxDynamicSharedMemorySize, 133120);
  const float* c0a = c0; const unsigned short* wpa = wp; const float* bpa = biasP;
  const unsigned short* xba = xbp;
  unsigned short* h0a = h0r; unsigned short* h1a = h1r;
  unsigned* ca = ctr; float* oa = out;
  void* args[] = {&c0a, &wpa, &bpa, &xba, &h0a, &h1a, &ca, &oa};
  hipError_t e = hipLaunchCooperativeKernel((const void*)klstm, dim3(NBLK), dim3(TPB),
                                            args, 133120, stream);
  if (e != hipSuccess) {
    hipLaunchKernelGGL(klstm, dim3(NBLK), dim3(TPB), 133120, stream,
                       c0a, wpa, bpa, xba, h0a, h1a, ca, oa);
  }
}

// Round 16
// 4790.414 us; speedup vs baseline: 1.2936x; 1.2936x over previous
//
#include <hip/hip_runtime.h>

// CustomLSTM on MI355X: persistent cooperative kernel (R13 skeleton, best).
// R16: per-step agent acquire-fence ELIMINATED — h fragments loaded with
// inline-asm `global_load_dwordx4 sc0 sc1` (coherent at MALL, no L2 inv
// needed). L2 stays warm for xb/out. Burst + vmcnt(0) + sched_barrier.

#define NBLK 256
#define TPB  512
#define T_   512
#define HS_OFF 33554432   // outputs floats
#define CS_OFF 33685504   // HS_OFF + 2*64*1024

typedef float  f32x4  __attribute__((ext_vector_type(4)));
typedef short  bf16x8 __attribute__((ext_vector_type(8)));

// ---- workspace byte offsets ----
#define WS_CTR  0u              // 139264: gctr[16][1024] | rctr[1024] | gflag[16][1024]
#define WS_W    139264u         // 4 * (4096*1024) bf16 = 32 MiB (permuted, [m][p][k])
#define WS_BIAS 33693696u       // 2*4096 f32
#define WS_XB   33726464u       // [T][B][D] bf16 = 64 MiB
#define WS_H0   100835328u      // ring: 2 * 65536 bf16, layout [oct][row][8]
#define WS_H1   101097472u
#define WS_MIN  101359616u

__device__ __forceinline__ unsigned short f2bf(float f) {
  union { float f; unsigned u; } v; v.f = f;
  return (unsigned short)((v.u + 0x7FFFu + ((v.u >> 16) & 1u)) >> 16);
}
__device__ __forceinline__ float fsig(float x) { return 1.0f / (1.0f + __expf(-x)); }
__device__ __forceinline__ float ftanh(float x) {
  x = fminf(15.0f, fmaxf(-15.0f, x));
  float e = __expf(2.0f * x);
  return (e - 1.0f) / (e + 1.0f);
}

// Permute+transpose+bf16 the 4 weight matrices: out[m][p][k] = bf16(W_m[k][orig(p)]),
// orig(p) = (p&3)*1024 + (p>>2)  (p = 4*j + gate). 64x64 tiles via LDS.
__global__ void kw(const float* __restrict__ Wx0, const float* __restrict__ Wh0,
                   const float* __restrict__ Wx1, const float* __restrict__ Wh1,
                   unsigned short* __restrict__ wp) {
  __shared__ float tile[64][65];
  int tb = blockIdx.x;
  int m  = tb >> 10;
  int kt = (tb >> 6) & 15;
  int nt = tb & 63;
  const float* W = (m == 0) ? Wx0 : (m == 1) ? Wh0 : (m == 2) ? Wx1 : Wh1;
  unsigned short* O = wp + (size_t)m * 4194304u;
  int k0 = kt * 64, n0 = nt * 64;
  int tx = threadIdx.x & 63, tg = threadIdx.x >> 6;
  for (int r = tg; r < 64; r += 4)
    tile[r][tx] = W[(size_t)(k0 + r) * 4096 + n0 + tx];
  __syncthreads();
  for (int r = tg; r < 64; r += 4) {
    int n = n0 + r;
    int p = ((n & 1023) << 2) | (n >> 10);
    O[(size_t)p * 1024 + k0 + tx] = f2bf(tile[tx][r]);
  }
}

// x [B][T][D] f32 -> xb [T*B][D] bf16 (row = t*64+b)
__global__ void kx(const float* __restrict__ x, unsigned short* __restrict__ xb) {
  int row = blockIdx.x;
  int t = row >> 6, b = row & 63;
  const float4* src = (const float4*)(x + ((size_t)b * 512 + t) * 1024);
  float4 f = src[threadIdx.x];
  ushort4 o; o.x = f2bf(f.x); o.y = f2bf(f.y); o.z = f2bf(f.z); o.w = f2bf(f.w);
  ((ushort4*)(xb + (size_t)row * 1024))[threadIdx.x] = o;
}

// bias permute + prime ring slot 1 with initial h states (bf16, [oct][row][8])
__global__ void kmisc(const float* __restrict__ b0, const float* __restrict__ b1,
                      const float* __restrict__ h0in,
                      float* __restrict__ biasP,
                      unsigned short* __restrict__ h0r, unsigned short* __restrict__ h1r) {
  int idx = blockIdx.x * 256 + threadIdx.x;
  if (idx < 8192) {
    int layer = idx >> 12, p = idx & 4095;
    int orig = (p & 3) * 1024 + (p >> 2);
    biasP[idx] = (layer ? b1 : b0)[orig];
  } else if (idx < 139264) {
    int e = idx - 8192;
    int layer = e >> 16, o = e & 65535;
    int row = o >> 10, col = o & 1023;
    unsigned short v = f2bf(h0in[layer * 65536 + o]);
    int dst = 65536 + (col >> 3) * 512 + row * 8 + (col & 7);
    if (layer) h1r[dst] = v; else h0r[dst] = v;
  }
}

// Persistent cooperative kernel. 256 blocks x 512 threads (8 waves).
// Wave w: rows 16*(w&3), K-half (w>>2)*512, finalizes layer (w>>2).
// All 4 weight slices in LDS; h fragments loaded COHERENT (sc0 sc1) in one
// asm burst — no per-step fence/inv anywhere.
__global__ void __launch_bounds__(TPB, 2)
klstm(const float* __restrict__ c0_in,
      const unsigned short* __restrict__ wp,
      const float* __restrict__ biasP,
      const unsigned short* __restrict__ xb,
      unsigned short* __restrict__ h0ring,
      unsigned short* __restrict__ h1ring,
      unsigned* __restrict__ ctrbase,
      float* __restrict__ out) {
  extern __shared__ char smem[];   // 32K Wx0 | 32K Wx1 | 32K Wh0 | 32K Wh1 | 8K red | 2K lh | 4K xred
  float* red  = (float*)(smem + 131072);
  float* lhb  = (float*)(smem + 139264);
  float* xred = (float*)(smem + 141312);
  unsigned* gctr  = ctrbase;               // [16][1024]
  unsigned* rctr  = ctrbase + 16384;       // [1024]
  unsigned* gflag = ctrbase + 17408;       // [16][1024]
  const int tid = threadIdx.x;
  const int w   = tid >> 6;
  const int l   = tid & 63;
  const int bid = blockIdx.x;
  const int n0  = bid * 16;
  const int layer = w >> 2;
  const int rbase = (w & 3) * 16;
  const int khalf = (w >> 2) * 512;
  const int grp   = bid >> 4;              // 16 groups of 16 blocks
  float* lh = lhb + w * 64;                // [16 rows][4 cols] f32 per wave

  // stage all 4 weight slices into LDS: slot0=Wx0(m0) slot1=Wx1(m2) slot2=Wh0(m1) slot3=Wh1(m3)
  {
    const int msrc[4] = {0, 2, 1, 3};
    for (int s = 0; s < 4; ++s) {
      const char* src = (const char*)(wp + (size_t)msrc[s] * 4194304u + (size_t)n0 * 1024u);
      char* dst = smem + s * 32768;
      for (int i = tid; i < 2048; i += TPB) {
        int sb = i << 4;
        int c  = sb >> 11;
        int kb = sb & 2047;
        *(uint4*)(dst + (c << 11) + (kb ^ ((c & 7) << 4))) = *(const uint4*)(src + sb);
      }
    }
  }

  const int jg = bid * 4 + ((l & 15) >> 2);   // global h column (gate finalize)
  const float biasv = biasP[layer * 4096 + n0 + (l & 15)];
  const int qb = l & ~3;

  float cr[4];
  #pragma unroll
  for (int v = 0; v < 4; ++v)
    cr[v] = c0_in[layer * 65536 + (rbase + (l >> 4) * 4 + v) * 1024 + jg];

  const int ae0  = (rbase + (l & 15)) * 1024 + khalf + (l >> 4) * 8;  // xb (row-major)
  const int hbase = ((khalf >> 3) + (l >> 4)) * 512 + (rbase + (l & 15)) * 8;
  const int lb0  = (l & 15) << 11;
  const int kb2  = khalf * 2 + (l >> 4) * 16;
  const int swz  = (l & 7) << 4;
  const int hsto = (bid >> 1) * 512 + 4 * (bid & 1);

  __syncthreads();                         // weight staging visible

  // prologue: x[0]@Wx0 slice for this wave
  f32x4 xacc = {0.f, 0.f, 0.f, 0.f};
  {
    #pragma unroll
    for (int kk = 0; kk < 16; ++kk) {
      bf16x8 ax = *(const bf16x8*)(xb + ae0 + kk * 32);
      bf16x8 b  = *(const bf16x8*)(smem + lb0 + ((kb2 + kk * 64) ^ swz));
      xacc = __builtin_amdgcn_mfma_f32_16x16x32_bf16(ax, b, xacc, 0, 0, 0);
    }
    if (w >= 4) {
      float* xr = xred + (size_t)(w & 3) * 256 + (size_t)l * 4;
      #pragma unroll
      for (int v = 0; v < 4; ++v) xr[v] = xacc[v];
    }
  }
  __syncthreads();

  for (int k = 0; k <= T_; ++k) {
    const unsigned short* h0p = h0ring + ((k + 1) & 1) * 65536;
    const unsigned short* h1p = h1ring + (k & 1) * 65536;

    // ---- coherent h burst: 32 x global_load_dwordx4 sc0 sc1 (MALL-direct) ----
    bf16x8 hf0[16], hf1[16];
    #pragma unroll
    for (int kk = 0; kk < 16; ++kk) {
      const unsigned short* a0p = h0p + hbase + kk * 2048;
      const unsigned short* a1p = h1p + hbase + kk * 2048;
      asm volatile("global_load_dwordx4 %0, %1, off sc0 sc1"
                   : "=v"(hf0[kk]) : "v"(a0p));
      asm volatile("global_load_dwordx4 %0, %1, off sc0 sc1"
                   : "=v"(hf1[kk]) : "v"(a1p));
    }
    asm volatile("s_waitcnt vmcnt(0)" ::: "memory");
    __builtin_amdgcn_sched_barrier(0);

    f32x4 acc0  = {0.f, 0.f, 0.f, 0.f};
    f32x4 acc1a = {0.f, 0.f, 0.f, 0.f};
    f32x4 acc1b = {0.f, 0.f, 0.f, 0.f};
    #pragma unroll
    for (int kk = 0; kk < 16; ++kk) {
      const int bo = lb0 + ((kb2 + kk * 64) ^ swz);
      bf16x8 bh0 = *(const bf16x8*)(smem + 65536 + bo);
      bf16x8 bx1 = *(const bf16x8*)(smem + 32768 + bo);
      bf16x8 bh1 = *(const bf16x8*)(smem + 98304 + bo);
      acc0  = __builtin_amdgcn_mfma_f32_16x16x32_bf16(hf0[kk], bh0, acc0, 0, 0, 0);
      acc1a = __builtin_amdgcn_mfma_f32_16x16x32_bf16(hf0[kk], bx1, acc1a, 0, 0, 0);
      acc1b = __builtin_amdgcn_mfma_f32_16x16x32_bf16(hf1[kk], bh1, acc1b, 0, 0, 0);
    }

    { // publish the other layer's partial for the partner wave
      float* rb = red + (size_t)(w * 64 + l) * 4;
      f32x4 other = layer ? acc0 : (acc1a + acc1b);
      #pragma unroll
      for (int v = 0; v < 4; ++v) rb[v] = other[v];
    }
    __syncthreads();

    f32x4 g = layer ? (acc1a + acc1b) : acc0;
    {
      const int pw = layer ? (w - 4) : (w + 4);
      const float* rb = red + (size_t)(pw * 64 + l) * 4;
      #pragma unroll
      for (int v = 0; v < 4; ++v) g[v] += rb[v];
    }
    if (w < 4) {   // + x@Wx0: own half (regs) + partner half (xred)
      const float* xr = xred + (size_t)w * 256 + (size_t)l * 4;
      #pragma unroll
      for (int v = 0; v < 4; ++v) g[v] += xacc[v] + xr[v];
    }

    const bool active = layer ? (k >= 1) : (k < T_);
    f32x4 outv = {0.f, 0.f, 0.f, 0.f};
    if (active) {
      unsigned short* hw = layer ? (h1ring + ((k + 1) & 1) * 65536)
                                 : (h0ring + (k & 1) * 65536);
      #pragma unroll
      for (int v = 0; v < 4; ++v) {
        float gv = g[v] + biasv;
        float gi = __shfl(gv, qb);
        float gf = __shfl(gv, qb | 1);
        float gn = __shfl(gv, qb | 2);
        float go = __shfl(gv, qb | 3);
        float i_ = fsig(gi), f_ = fsig(gf), n_ = ftanh(gn), o_ = fsig(go);
        float c = f_ * cr[v] + i_ * n_;
        cr[v] = c;
        float h = o_ * ftanh(c);
        if ((l & 3) == 0)
          lh[((l >> 4) * 4 + v) * 4 + ((l & 15) >> 2)] = h;   // repack tile
      }
      if (l < 16) {   // same-wave read-back: coalesced 8B agent store
        f32x4 h4 = *(f32x4*)(lh + l * 4);
        outv = h4;
        ushort4 u4;
        u4.x = f2bf(h4[0]); u4.y = f2bf(h4[1]); u4.z = f2bf(h4[2]); u4.w = f2bf(h4[3]);
        union { ushort4 s; unsigned long long q; } pk; pk.s = u4;
        __hip_atomic_store((unsigned long long*)(hw + hsto + (rbase + l) * 8), pk.q,
                           __ATOMIC_RELAXED, __HIP_MEMORY_SCOPE_AGENT);
      }
    }

    // ---- barrier arrival (16x16 tree); NO fence anywhere ----
    if (k < T_) {
      __syncthreads();                      // drain h stores block-wide
      if (tid == 0) {
        unsigned old = __hip_atomic_fetch_add(&gctr[grp * 1024 + k], 1u,
                                              __ATOMIC_RELAXED, __HIP_MEMORY_SCOPE_AGENT);
        if (old == 15u) {
          unsigned oldr = __hip_atomic_fetch_add(&rctr[k], 1u,
                                                 __ATOMIC_RELAXED, __HIP_MEMORY_SCOPE_AGENT);
          if (oldr == 15u) {
            #pragma unroll
            for (int gg = 0; gg < 16; ++gg)
              __hip_atomic_store(&gflag[gg * 1024 + k], 1u,
                                 __ATOMIC_RELAXED, __HIP_MEMORY_SCOPE_AGENT);
          }
        }
      }
    }

    // ---- overlap window: out stores + x[k+1]@Wx0 slice (dead-time work) ----
    if (active && l < 16) {
      const int row = rbase + l;
      if (layer) {
        *(f32x4*)(out + (size_t)row * 524288u + (size_t)(k - 1) * 1024u + bid * 4) = outv;
        if (k == T_)
          *(f32x4*)(out + HS_OFF + 65536 + row * 1024 + bid * 4) = outv;
      } else if (k == T_ - 1) {
        *(f32x4*)(out + HS_OFF + row * 1024 + bid * 4) = outv;
      }
    }
    if (k + 1 < T_) {
      const unsigned short* xt = xb + (size_t)(k + 1) * 65536u;
      f32x4 xa = {0.f, 0.f, 0.f, 0.f};
      #pragma unroll
      for (int kk = 0; kk < 16; ++kk) {
        bf16x8 ax = *(const bf16x8*)(xt + ae0 + kk * 32);
        bf16x8 b  = *(const bf16x8*)(smem + lb0 + ((kb2 + kk * 64) ^ swz));
        xa = __builtin_amdgcn_mfma_f32_16x16x32_bf16(ax, b, xa, 0, 0, 0);
      }
      if (w >= 4) {   // publish K-half-1 partial; consumed at step k+1 finalize
        float* xr = xred + (size_t)(w & 3) * 256 + (size_t)l * 4;
        #pragma unroll
        for (int v = 0; v < 4; ++v) xr[v] = xa[v];
      } else {
        xacc = xa;
      }
    }

    // ---- barrier wait (per-group flag line); syncthreads = ordering fence ----
    if (k < T_) {
      if (tid == 0) {
        unsigned spins = 0;
        while (__hip_atomic_load(&gflag[grp * 1024 + k], __ATOMIC_RELAXED, __HIP_MEMORY_SCOPE_AGENT) == 0u) {
          __builtin_amdgcn_s_sleep(1);
          if (++spins > 67108864u) break;   // safety: never wedge the GPU
        }
      }
      __syncthreads();
    }
  }

  // final cell states (rare, scattered is fine)
  if ((l & 3) == 0) {
    #pragma unroll
    for (int v = 0; v < 4; ++v)
      out[CS_OFF + layer * 65536 + (rbase + (l >> 4) * 4 + v) * 1024 + jg] = cr[v];
  }
}

extern "C" void kernel_launch(void* const* d_in, const int* in_sizes, int n_in,
                              void* d_out, int out_size, void* d_ws, size_t ws_size,
                              hipStream_t stream) {
  const float* x   = (const float*)d_in[0];
  const float* h0  = (const float*)d_in[1];
  const float* c0  = (const float*)d_in[2];
  const float* Wx0 = (const float*)d_in[3];
  const float* Wh0 = (const float*)d_in[4];
  const float* b0  = (const float*)d_in[5];
  const float* Wx1 = (const float*)d_in[6];
  const float* Wh1 = (const float*)d_in[7];
  const float* b1  = (const float*)d_in[8];
  float* out = (float*)d_out;
  char* ws = (char*)d_ws;
  if (ws_size < (size_t)WS_MIN) return;   // workspace too small -> fail loudly

  unsigned* ctr       = (unsigned*)(ws + WS_CTR);
  unsigned short* wp  = (unsigned short*)(ws + WS_W);
  float* biasP        = (float*)(ws + WS_BIAS);
  unsigned short* xbp = (unsigned short*)(ws + WS_XB);
  unsigned short* h0r = (unsigned short*)(ws + WS_H0);
  unsigned short* h1r = (unsigned short*)(ws + WS_H1);

  (void)hipMemsetAsync(ctr, 0, 139264, stream);
  hipLaunchKernelGGL(kw,    dim3(4096),  dim3(256), 0, stream, Wx0, Wh0, Wx1, Wh1, wp);
  hipLaunchKernelGGL(kx,    dim3(32768), dim3(256), 0, stream, x, xbp);
  hipLaunchKernelGGL(kmisc, dim3(544),   dim3(256), 0, stream, b0, b1, h0, biasP, h0r, h1r);

  (void)hipFuncSetAttribute((const void*)klstm, hipFuncAttributeMaxDynamicSharedMemorySize, 145408);
  const float* c0a = c0; const unsigned short* wpa = wp; const float* bpa = biasP;
  const unsigned short* xba = xbp;
  unsigned short* h0a = h0r; unsigned short* h1a = h1r;
  unsigned* ca = ctr; float* oa = out;
  void* args[] = {&c0a, &wpa, &bpa, &xba, &h0a, &h1a, &ca, &oa};
  hipError_t e = hipLaunchCooperativeKernel((const void*)klstm, dim3(NBLK), dim3(TPB),
                                            args, 145408, stream);
  if (e != hipSuccess) {
    hipLaunchKernelGGL(klstm, dim3(NBLK), dim3(TPB), 145408, stream,
                       c0a, wpa, bpa, xba, h0a, h1a, ca, oa);
  }
}